// Round 3
// baseline (285.583 us; speedup 1.0000x reference)
//
#include <hip/hip_runtime.h>
#include <cmath>

#define BATCH 32
#define CCH 512
#define HW 4096
#define KCL 17
#define TS 64
#define NT 4            // tiles per block (4*64 = 256 px per slice)
#define NSLICE 16
#define NTHREADS 512

// LDS byte offsets
#define LX_BYTES (CCH * TS * 2)          // 65536: bf16 x-tile [512c][64px], 16B-slot XOR swizzle
#define R_OFF LX_BYTES                   // ushort[4][17][64] = 8704 B (bf16 cam partials)
#define R_BYTES (4 * KCL * TS * 2)
#define ST_OFF (R_OFF + R_BYTES)         // float[64][20] sigmoid table
#define ST_BYTES (TS * 20 * 4)
#define SMEM_BYTES (ST_OFF + ST_BYTES)   // 79360 B -> 2 blocks/CU

__global__ void zero_out_kernel(float* __restrict__ out, int n) {
  int i = blockIdx.x * blockDim.x + threadIdx.x;
  if (i < n) out[i] = 0.f;
}

__global__ void transpose_w_kernel(const float* __restrict__ w, float* __restrict__ wT) {
  int c = threadIdx.x;  // 512 threads
  #pragma unroll
  for (int k = 0; k < 20; ++k)
    wT[c * 20 + k] = (k < KCL) ? w[k * CCH + c] : 0.f;
}

__device__ __forceinline__ unsigned pack_bf16(float a, float b) {
  // round-half-up bf16 pack: lo = a, hi = b
  unsigned ua = (__float_as_uint(a) + 0x8000u) >> 16;
  unsigned ub = (__float_as_uint(b) + 0x8000u) & 0xFFFF0000u;
  return ua | ub;
}
__device__ __forceinline__ float bf_lo(unsigned u) { return __uint_as_float(u << 16); }
__device__ __forceinline__ float bf_hi(unsigned u) { return __uint_as_float(u & 0xFFFF0000u); }

template <bool USE_WT>
__global__ __launch_bounds__(NTHREADS, 4)
void ssam_fused(const float* __restrict__ x, const float* __restrict__ w,
                const float* __restrict__ bias, const float* __restrict__ wT,
                float* __restrict__ out_g, float* __restrict__ out_sf) {
  extern __shared__ char smem[];
  unsigned* lxu = (unsigned*)smem;              // bf16 tile as u32: row c = 32 u32 (64 px)
  uint4* lxu4 = (uint4*)smem;                   // row c = 8 uint4 slots
  const unsigned short* lds16 = (const unsigned short*)smem;
  unsigned short* Rb = (unsigned short*)(smem + R_OFF);
  unsigned* R32 = (unsigned*)(smem + R_OFF);
  float* sT = (float*)(smem + ST_OFF);

  const int t = threadIdx.x;
  const int lane = t & 63;
  const int wv = __builtin_amdgcn_readfirstlane(t >> 6);
  const int b = blockIdx.x >> 4;
  const int slice = blockIdx.x & 15;
  const size_t xbase = (size_t)b * CCH * HW;

  // phase-2 mapping: thread owns 4 channels {clo+128i} x k-quad kq
  const int clo = t & 127;
  const int kq = t >> 7;            // uniform per wave (t>>7 = wv>>1)
  const int kbase = kq * 4;
  int crow[4], cx[4];
  #pragma unroll
  for (int i = 0; i < 4; ++i) {
    int c = clo + 128 * i;
    crow[i] = c * 8;                // uint4 slots per row
    cx[i] = c & 7;
  }

  // combine mapping: pair p = t -> k = t>>5 (0..15), jj = t&31 -> px {2jj,2jj+1}
  const int ck = t >> 5;
  const int cj = t & 31;
  const float bias_reg = bias[ck];
  const float bias16 = bias[16];

  // phase-1 lane addressing
  const int sl = lane >> 3, off8 = lane & 7;

  float gacc = 0.f, gacc2 = 0.f;
  float acc[4][4], acc4[4];
  #pragma unroll
  for (int a = 0; a < 4; ++a) {
    acc4[a] = 0.f;
    #pragma unroll
    for (int i = 0; i < 4; ++i) acc[a][i] = 0.f;
  }

  for (int tile = 0; tile < NT; ++tile) {
    const int p0 = slice * (TS * NT) + tile * TS;

    // ---- stage: f32 global -> bf16 LDS, slot swizzle phys = (q>>1)^(c&7) ----
    #pragma unroll
    for (int j = 0; j < 16; ++j) {
      int m = t + NTHREADS * j;     // 8192 float4 quads (512 rows x 16)
      int c = m >> 4;
      int q = m & 15;               // px quad 4q..4q+3
      const float4 v = *reinterpret_cast<const float4*>(x + xbase + (size_t)c * HW + p0 + 4 * q);
      unsigned u0 = pack_bf16(v.x, v.y);
      unsigned u1 = pack_bf16(v.z, v.w);
      int slot = (q >> 1) ^ (c & 7);
      *reinterpret_cast<uint2*>(smem + c * 128 + slot * 16 + (q & 1) * 8) =
          make_uint2(u0, u1);
    }
    __syncthreads();  // (1)

    // ---- phase 1: cam partials; wave wv -> channels [64wv,64wv+64), lane = px ----
    float cam[KCL];
    #pragma unroll
    for (int k = 0; k < KCL; ++k) cam[k] = 0.f;
    const int c0 = wv * 64;
    #pragma unroll 4
    for (int cc = 0; cc < 64; ++cc) {
      const int c = c0 + cc;
      const unsigned short h = lds16[c * 64 + ((sl ^ (c & 7)) << 3) + off8];
      const float xv = __uint_as_float((unsigned)h << 16);
      if (USE_WT) {
        #pragma unroll
        for (int k = 0; k < KCL; ++k) cam[k] = fmaf(wT[c * 20 + k], xv, cam[k]);
      } else {
        #pragma unroll
        for (int k = 0; k < KCL; ++k) cam[k] = fmaf(w[k * CCH + c], xv, cam[k]);
      }
    }

    // ---- flat 2-stage reduce over 8 wave partials (bf16 in LDS) ----
    if (wv >= 4) {
      #pragma unroll
      for (int k = 0; k < KCL; ++k)
        Rb[(wv - 4) * 1088 + k * 64 + lane] =
            (unsigned short)((__float_as_uint(cam[k]) + 0x8000u) >> 16);
    }
    __syncthreads();  // (2)
    if (wv < 4) {
      #pragma unroll
      for (int k = 0; k < KCL; ++k) {
        int idx = wv * 1088 + k * 64 + lane;
        float v = __uint_as_float((unsigned)Rb[idx] << 16) + cam[k];
        Rb[idx] = (unsigned short)((__float_as_uint(v) + 0x8000u) >> 16);
      }
    }
    __syncthreads();  // (3)

    // ---- combine 4 slots + bias -> sigmoid -> sT; accumulate g ----
    {
      float v0 = bias_reg, v1 = bias_reg;
      #pragma unroll
      for (int s = 0; s < 4; ++s) {
        unsigned u = R32[s * 544 + ck * 32 + cj];
        v0 += bf_lo(u);
        v1 += bf_hi(u);
      }
      sT[(2 * cj) * 20 + ck] = 1.f / (1.f + __expf(-v0));
      sT[(2 * cj + 1) * 20 + ck] = 1.f / (1.f + __expf(-v1));
      gacc += v0 + v1;
      if (t < 32) {  // extra pairs for k=16
        float u0 = bias16, u1 = bias16;
        #pragma unroll
        for (int s = 0; s < 4; ++s) {
          unsigned u = R32[s * 544 + 512 + t];
          u0 += bf_lo(u);
          u1 += bf_hi(u);
        }
        sT[(2 * t) * 20 + 16] = 1.f / (1.f + __expf(-u0));
        sT[(2 * t + 1) * 20 + 16] = 1.f / (1.f + __expf(-u1));
        gacc2 += u0 + u1;
      }
    }
    __syncthreads();  // (4)

    // ---- phase 2: sf accumulate; thread = 4 c's x 4(5) k's over 64 px ----
    #pragma unroll 2
    for (int pg = 0; pg < 8; ++pg) {
      uint4 u[4];
      #pragma unroll
      for (int i = 0; i < 4; ++i) u[i] = lxu4[crow[i] + (pg ^ cx[i])];
      #pragma unroll
      for (int j = 0; j < 8; ++j) {
        const int px = pg * 8 + j;
        const float4 sg = *reinterpret_cast<const float4*>(sT + px * 20 + kbase);
        float s16 = 0.f;
        if (kq == 3) s16 = sT[px * 20 + 16];
        #pragma unroll
        for (int i = 0; i < 4; ++i) {
          unsigned wrd = ((const unsigned*)&u[i])[j >> 1];
          const float xf = (j & 1) ? bf_hi(wrd) : bf_lo(wrd);
          acc[0][i] = fmaf(sg.x, xf, acc[0][i]);
          acc[1][i] = fmaf(sg.y, xf, acc[1][i]);
          acc[2][i] = fmaf(sg.z, xf, acc[2][i]);
          acc[3][i] = fmaf(sg.w, xf, acc[3][i]);
          if (kq == 3) acc4[i] = fmaf(s16, xf, acc4[i]);
        }
      }
    }
    __syncthreads();  // (5) protect lx/sT/R before next tile
  }

  // ---- epilogue ----
  const float inv = 1.f / 4096.f;
  #pragma unroll
  for (int kk = 0; kk < 4; ++kk) {
    #pragma unroll
    for (int i = 0; i < 4; ++i) {
      atomicAdd(out_sf + (size_t)(b * KCL + kbase + kk) * CCH + (clo + 128 * i),
                acc[kk][i] * inv);
    }
  }
  if (kq == 3) {
    #pragma unroll
    for (int i = 0; i < 4; ++i)
      atomicAdd(out_sf + (size_t)(b * KCL + 16) * CCH + (clo + 128 * i), acc4[i] * inv);
  }
  // g: reduce within each 32-thread k-group
  {
    float gv = gacc;
    #pragma unroll
    for (int o = 16; o > 0; o >>= 1) gv += __shfl_xor(gv, o, 32);
    if ((t & 31) == 0) atomicAdd(out_g + b * KCL + ck, gv * inv);
    if (t < 32) {
      float g2 = gacc2;
      #pragma unroll
      for (int o = 16; o > 0; o >>= 1) g2 += __shfl_xor(g2, o, 32);
      if (t == 0) atomicAdd(out_g + b * KCL + 16, g2 * inv);
    }
  }
}

extern "C" void kernel_launch(void* const* d_in, const int* in_sizes, int n_in,
                              void* d_out, int out_size, void* d_ws, size_t ws_size,
                              hipStream_t stream) {
  const float* x = (const float*)d_in[0];
  const float* w = (const float*)d_in[1];
  const float* bias = (const float*)d_in[2];
  float* out = (float*)d_out;
  float* outg = out;                  // (32,17)
  float* outsf = out + BATCH * KCL;   // (32,17,512)
  float* wT = (float*)d_ws;

  const int total = BATCH * KCL + BATCH * KCL * CCH;  // 279072
  zero_out_kernel<<<(total + 511) / 512, 512, 0, stream>>>(out, total);

  const size_t smem = SMEM_BYTES;
  const bool use_wt = (d_ws != nullptr) && (ws_size >= 512 * 20 * sizeof(float));

  if (use_wt) {
    transpose_w_kernel<<<1, 512, 0, stream>>>(w, wT);
    hipFuncSetAttribute((const void*)ssam_fused<true>,
                        hipFuncAttributeMaxDynamicSharedMemorySize, (int)smem);
    ssam_fused<true><<<BATCH * NSLICE, NTHREADS, smem, stream>>>(x, w, bias, wT, outg, outsf);
  } else {
    hipFuncSetAttribute((const void*)ssam_fused<false>,
                        hipFuncAttributeMaxDynamicSharedMemorySize, (int)smem);
    ssam_fused<false><<<BATCH * NSLICE, NTHREADS, smem, stream>>>(x, w, bias, wT, outg, outsf);
  }
}

// Round 4
// 264.102 us; speedup vs baseline: 1.0813x; 1.0813x over previous
//
#include <hip/hip_runtime.h>
#include <cmath>

#define BATCH 32
#define CCH 512
#define HW 4096
#define KCL 17
#define TS 64
#define NT 4            // tiles per block (4*64 = 256 px per slice)
#define NSLICE 16
#define NTHREADS 512

// LDS: x-tile bf16 [512ch][64px] swizzled (65536 B) + sigT bf16 [32cls][64px] swizzled (4096 B)
#define SIGT_OFF 65536
#define SMEM_BYTES (65536 + 4096)

#define PART_FLOATS (512 * 512 * 32)           // [block][ch][cls32]
#define PART_BYTES (PART_FLOATS * 4)           // 33554432
#define WT_BYTES (512 * 20 * 4)                // 40960

typedef __attribute__((ext_vector_type(8))) short short8;
typedef __attribute__((ext_vector_type(16))) float f32x16;

__global__ void zero_out_kernel(float* __restrict__ out, int n) {
  int i = blockIdx.x * blockDim.x + threadIdx.x;
  if (i < n) out[i] = 0.f;
}

__global__ void transpose_w_kernel(const float* __restrict__ w, float* __restrict__ wT) {
  int c = threadIdx.x;  // 512 threads
  #pragma unroll
  for (int k = 0; k < 20; ++k)
    wT[c * 20 + k] = (k < KCL) ? w[k * CCH + c] : 0.f;
}

__device__ __forceinline__ unsigned pack_bf16(float a, float b) {
  unsigned ua = (__float_as_uint(a) + 0x8000u) >> 16;
  unsigned ub = (__float_as_uint(b) + 0x8000u) & 0xFFFF0000u;
  return ua | ub;
}
__device__ __forceinline__ unsigned short to_bf16(float v) {
  return (unsigned short)((__float_as_uint(v) + 0x8000u) >> 16);
}

// Final reduce: sum 16 slice-partials -> out_sf
__global__ void reduce_sf_kernel(const float* __restrict__ part, float* __restrict__ out_sf) {
  int tid = blockIdx.x * blockDim.x + threadIdx.x;  // 524288 total
  int b = tid >> 14;
  int rem = tid & 16383;
  int ch = rem >> 5;
  int cls = rem & 31;
  if (cls >= KCL) return;
  const int stride = 512 * 32;
  size_t base = ((size_t)(b * 16) * 512 + ch) * 32 + cls;
  float s = 0.f;
  #pragma unroll
  for (int sl = 0; sl < 16; ++sl) s += part[base + (size_t)sl * stride];
  out_sf[(size_t)(b * KCL + cls) * 512 + ch] = s * (1.f / 4096.f);
}

template <bool USE_WS, bool USE_WT>
__global__ __launch_bounds__(NTHREADS, 4)
void ssam_fused(const float* __restrict__ x, const float* __restrict__ w,
                const float* __restrict__ bias, const float* __restrict__ wT,
                float* __restrict__ out_g, float* __restrict__ out_sf,
                float* __restrict__ part) {
  extern __shared__ char smem[];
  const unsigned short* lx16 = (const unsigned short*)smem;
  unsigned short* sT16 = (unsigned short*)(smem + SIGT_OFF);

  const int t = threadIdx.x;
  const int lane = t & 63;
  const int wv = __builtin_amdgcn_readfirstlane(t >> 6);  // wave id 0..7
  const int b = blockIdx.x >> 4;
  const int slice = blockIdx.x & 15;
  const size_t xbase = (size_t)b * CCH * HW;

  const int j = lane & 7;    // ch-sub (phase A) / class index
  const int pj = lane >> 3;  // px-sub (phase A): px = wv*8 + pj
  const int cls = lane & 31; // phase B: class (B) / ch-sub (A operand)
  const int h = lane >> 5;   // phase B k-half

  const float b0 = bias[j];
  const float b1 = bias[j + 8];
  const float b2 = bias[16];

  f32x16 acc0, acc1;
  #pragma unroll
  for (int i = 0; i < 16; ++i) { acc0[i] = 0.f; acc1[i] = 0.f; }
  float gA = 0.f, gB = 0.f, gC = 0.f;

  // zero sigT pad rows 17..31 (persist across tiles; only rows 0..16 rewritten)
  if (t < 480) ((unsigned*)(smem + SIGT_OFF + 17 * 128))[t] = 0u;

  const int xoff = ((wv ^ j) << 3) + pj;  // halfword offset within ch row (phase A)
  const float* wrow = USE_WT ? (wT + j * 20) : nullptr;

  for (int tile = 0; tile < NT; ++tile) {
    const int p0 = slice * (TS * NT) + tile * TS;

    // ---- stage: f32 global -> bf16 LDS, slot swizzle phys = (p>>3)^(c&7) ----
    #pragma unroll
    for (int jj = 0; jj < 16; ++jj) {
      int m = t + NTHREADS * jj;  // 8192 quads (512 rows x 16)
      int c = m >> 4;
      int q = m & 15;
      const float4 v = *reinterpret_cast<const float4*>(x + xbase + (size_t)c * HW + p0 + 4 * q);
      unsigned u0 = pack_bf16(v.x, v.y);
      unsigned u1 = pack_bf16(v.z, v.w);
      int slot = (q >> 1) ^ (c & 7);
      *reinterpret_cast<uint2*>(smem + c * 128 + slot * 16 + (q & 1) * 8) = make_uint2(u0, u1);
    }
    __syncthreads();  // (1)

    // ---- phase A: cam partials; lane covers px = wv*8+pj, ch = j+8c ----
    float cam[KCL];
    #pragma unroll
    for (int k = 0; k < KCL; ++k) cam[k] = 0.f;
    #pragma unroll 2
    for (int c = 0; c < 64; ++c) {
      const int ch = j + 8 * c;
      const unsigned short hx = lx16[ch * 64 + xoff];
      const float xv = __uint_as_float((unsigned)hx << 16);
      if (USE_WT) {
        const float4 w0 = *reinterpret_cast<const float4*>(wrow + c * 160);
        const float4 w1 = *reinterpret_cast<const float4*>(wrow + c * 160 + 4);
        const float4 w2 = *reinterpret_cast<const float4*>(wrow + c * 160 + 8);
        const float4 w3 = *reinterpret_cast<const float4*>(wrow + c * 160 + 12);
        const float w16v = wrow[c * 160 + 16];
        cam[0] = fmaf(w0.x, xv, cam[0]);  cam[1] = fmaf(w0.y, xv, cam[1]);
        cam[2] = fmaf(w0.z, xv, cam[2]);  cam[3] = fmaf(w0.w, xv, cam[3]);
        cam[4] = fmaf(w1.x, xv, cam[4]);  cam[5] = fmaf(w1.y, xv, cam[5]);
        cam[6] = fmaf(w1.z, xv, cam[6]);  cam[7] = fmaf(w1.w, xv, cam[7]);
        cam[8] = fmaf(w2.x, xv, cam[8]);  cam[9] = fmaf(w2.y, xv, cam[9]);
        cam[10] = fmaf(w2.z, xv, cam[10]); cam[11] = fmaf(w2.w, xv, cam[11]);
        cam[12] = fmaf(w3.x, xv, cam[12]); cam[13] = fmaf(w3.y, xv, cam[13]);
        cam[14] = fmaf(w3.z, xv, cam[14]); cam[15] = fmaf(w3.w, xv, cam[15]);
        cam[16] = fmaf(w16v, xv, cam[16]);
      } else {
        #pragma unroll
        for (int k = 0; k < KCL; ++k) cam[k] = fmaf(w[k * CCH + ch], xv, cam[k]);
      }
    }
    // butterfly over ch-sub bits (lanes j=0..7 within px group)
    #pragma unroll
    for (int k = 0; k < KCL; ++k) {
      cam[k] += __shfl_xor(cam[k], 1, 64);
      cam[k] += __shfl_xor(cam[k], 2, 64);
      cam[k] += __shfl_xor(cam[k], 4, 64);
    }

    // ---- sigmoid -> sigT (bf16), g accumulate. lane j handles classes j, j+8, (j==0: 16)
    {
      float c0 = 0.f, c1 = 0.f;
      #pragma unroll
      for (int k = 0; k < 8; ++k) {
        if (j == k) { c0 = cam[k]; c1 = cam[k + 8]; }
      }
      const float cf0 = c0 + b0;
      const float cf1 = c1 + b1;
      gA += cf0;
      gB += cf1;
      const float s0 = 1.f / (1.f + __expf(-cf0));
      const float s1 = 1.f / (1.f + __expf(-cf1));
      const int wslot = ((wv ^ j) << 3) + pj;
      sT16[j * 64 + wslot] = to_bf16(s0);
      sT16[(j + 8) * 64 + wslot] = to_bf16(s1);
      if (j == 0) {
        const float cf2 = cam[16] + b2;
        gC += cf2;
        sT16[16 * 64 + (wv << 3) + pj] = to_bf16(1.f / (1.f + __expf(-cf2)));
      }
    }
    __syncthreads();  // (2)

    // ---- phase B: sf^T[ch][cls] += x[ch][px] @ sig^T[px][cls] via MFMA 32x32x16 ----
    const int ch0 = wv * 32 + cls;  // m-tile 0 row; m-tile 1 = +256
    #pragma unroll
    for (int ks = 0; ks < 4; ++ks) {
      const int slot = (2 * ks + h) ^ (cls & 7);  // same for A and B (rows ≡ cls mod 8)
      const short8 bf = *reinterpret_cast<const short8*>(smem + SIGT_OFF + cls * 128 + slot * 16);
      const short8 a0 = *reinterpret_cast<const short8*>(smem + ch0 * 128 + slot * 16);
      const short8 a1 = *reinterpret_cast<const short8*>(smem + (ch0 + 256) * 128 + slot * 16);
      acc0 = __builtin_amdgcn_mfma_f32_32x32x16_bf16(a0, bf, acc0, 0, 0, 0);
      acc1 = __builtin_amdgcn_mfma_f32_32x32x16_bf16(a1, bf, acc1, 0, 0, 0);
    }
    __syncthreads();  // (3) protect lx/sigT before next staging
  }

  // ---- epilogue: sf partials ----
  const float inv = 1.f / 4096.f;
  if (USE_WS) {
    float* pblk = part + (size_t)blockIdx.x * (512 * 32);
    #pragma unroll
    for (int r = 0; r < 16; ++r) {
      const int chr = wv * 32 + (r & 3) + 8 * (r >> 2) + 4 * h;
      pblk[chr * 32 + cls] = acc0[r];
      pblk[(chr + 256) * 32 + cls] = acc1[r];
    }
  } else {
    if (cls < KCL) {
      #pragma unroll
      for (int r = 0; r < 16; ++r) {
        const int chr = wv * 32 + (r & 3) + 8 * (r >> 2) + 4 * h;
        atomicAdd(out_sf + (size_t)(b * KCL + cls) * 512 + chr, acc0[r] * inv);
        atomicAdd(out_sf + (size_t)(b * KCL + cls) * 512 + chr + 256, acc1[r] * inv);
      }
    }
  }

  // ---- g: butterfly over px-sub bits, then one atomic per class per wave ----
  #pragma unroll
  for (int off = 8; off < 64; off <<= 1) {
    gA += __shfl_xor(gA, off, 64);
    gB += __shfl_xor(gB, off, 64);
    gC += __shfl_xor(gC, off, 64);
  }
  if (lane < 8) {
    atomicAdd(out_g + b * KCL + lane, gA * inv);
    atomicAdd(out_g + b * KCL + 8 + lane, gB * inv);
  }
  if (lane == 0) atomicAdd(out_g + b * KCL + 16, gC * inv);
}

extern "C" void kernel_launch(void* const* d_in, const int* in_sizes, int n_in,
                              void* d_out, int out_size, void* d_ws, size_t ws_size,
                              hipStream_t stream) {
  const float* x = (const float*)d_in[0];
  const float* w = (const float*)d_in[1];
  const float* bias = (const float*)d_in[2];
  float* out = (float*)d_out;
  float* outg = out;                  // (32,17)
  float* outsf = out + BATCH * KCL;   // (32,17,512)
  float* wsf = (float*)d_ws;

  const int total = BATCH * KCL + BATCH * KCL * CCH;
  zero_out_kernel<<<(total + 511) / 512, 512, 0, stream>>>(out, total);

  const bool use_ws = (d_ws != nullptr) && (ws_size >= (size_t)PART_BYTES + WT_BYTES);
  const bool use_wt = (d_ws != nullptr) && (ws_size >= WT_BYTES);
  float* part = use_ws ? wsf : nullptr;
  float* wT = use_ws ? (wsf + PART_FLOATS) : wsf;

  if (use_wt) transpose_w_kernel<<<1, 512, 0, stream>>>(w, wT);

  const size_t smem = SMEM_BYTES;
  if (use_ws) {
    hipFuncSetAttribute((const void*)ssam_fused<true, true>,
                        hipFuncAttributeMaxDynamicSharedMemorySize, (int)smem);
    ssam_fused<true, true><<<BATCH * NSLICE, NTHREADS, smem, stream>>>(
        x, w, bias, wT, outg, outsf, part);
    reduce_sf_kernel<<<1024, 512, 0, stream>>>(part, outsf);
  } else if (use_wt) {
    hipFuncSetAttribute((const void*)ssam_fused<false, true>,
                        hipFuncAttributeMaxDynamicSharedMemorySize, (int)smem);
    ssam_fused<false, true><<<BATCH * NSLICE, NTHREADS, smem, stream>>>(
        x, w, bias, wT, outg, outsf, nullptr);
  } else {
    hipFuncSetAttribute((const void*)ssam_fused<false, false>,
                        hipFuncAttributeMaxDynamicSharedMemorySize, (int)smem);
    ssam_fused<false, false><<<BATCH * NSLICE, NTHREADS, smem, stream>>>(
        x, w, bias, wT, outg, outsf, nullptr);
  }
}

// Round 5
// 128.025 us; speedup vs baseline: 2.2307x; 2.0629x over previous
//
#include <hip/hip_runtime.h>
#include <cmath>

#define BATCH 32
#define CCH 512
#define HW 4096
#define KCL 17

typedef __attribute__((ext_vector_type(8))) short short8;
typedef __attribute__((ext_vector_type(16))) float f32x16;

__device__ __forceinline__ unsigned pack_bf16(float a, float b) {
  unsigned ua = (__float_as_uint(a) + 0x8000u) >> 16;
  unsigned ub = (__float_as_uint(b) + 0x8000u) & 0xFFFF0000u;
  return ua | ub;
}
__device__ __forceinline__ float bf_lo(unsigned u) { return __uint_as_float(u << 16); }
__device__ __forceinline__ float bf_hi(unsigned u) { return __uint_as_float(u & 0xFFFF0000u); }

// ws layout (bytes)
#define WT_OFF 0
#define WT_BYTES (CCH * 20 * 4)                 // 40960
#define PART_OFF WT_BYTES
#define PART_BYTES (BATCH * 4 * KCL * HW * 2)   // 17825792  bf16 [b][slab4][17][4096]
#define SIG_OFF (PART_OFF + PART_BYTES)
#define SIG_BYTES (BATCH * 32 * HW * 2)         // 8388608   bf16 [b][32pad][4096]
#define WS_NEED (SIG_OFF + SIG_BYTES)           // 26255360

__global__ void transpose_w_kernel(const float* __restrict__ w, float* __restrict__ wT) {
  int c = threadIdx.x;  // 512 threads
  #pragma unroll
  for (int k = 0; k < 20; ++k)
    wT[c * 20 + k] = (k < KCL) ? w[k * CCH + c] : 0.f;
}

// K1: cam partials over 128-ch slabs. No LDS, no barriers, pure stream.
__global__ __launch_bounds__(512)
void k1_campart(const float* __restrict__ x, const float* __restrict__ wT,
                unsigned short* __restrict__ part) {
  const int blk = blockIdx.x;            // 256 = b*8 + slab*2 + pxq
  const int b = blk >> 3;
  const int slab = (blk >> 1) & 3;
  const int pxq = blk & 1;
  const int px0 = pxq * 2048 + threadIdx.x * 4;
  const float* xp = x + (size_t)(b * CCH + slab * 128) * HW + px0;

  float cam[KCL][4];
  #pragma unroll
  for (int k = 0; k < KCL; ++k)
    #pragma unroll
    for (int i = 0; i < 4; ++i) cam[k][i] = 0.f;

  #pragma unroll 4
  for (int c = 0; c < 128; ++c) {
    const float4 v = *reinterpret_cast<const float4*>(xp + (size_t)c * HW);
    const float* wr = wT + (slab * 128 + c) * 20;   // lane-uniform -> s_load
    #pragma unroll
    for (int k = 0; k < KCL; ++k) {
      cam[k][0] = fmaf(wr[k], v.x, cam[k][0]);
      cam[k][1] = fmaf(wr[k], v.y, cam[k][1]);
      cam[k][2] = fmaf(wr[k], v.z, cam[k][2]);
      cam[k][3] = fmaf(wr[k], v.w, cam[k][3]);
    }
  }

  unsigned short* pp = part + ((size_t)b * 4 + slab) * KCL * HW + px0;
  #pragma unroll
  for (int k = 0; k < KCL; ++k) {
    uint2 u = make_uint2(pack_bf16(cam[k][0], cam[k][1]), pack_bf16(cam[k][2], cam[k][3]));
    *reinterpret_cast<uint2*>(pp + (size_t)k * HW) = u;
  }
}

// K2: reduce 4 slabs + bias -> sigmoid (bf16) + exact g store.
__global__ __launch_bounds__(512)
void k2_sig(const unsigned short* __restrict__ part, const float* __restrict__ bias,
            float* __restrict__ out_g, unsigned short* __restrict__ sig) {
  const int b = blockIdx.x / KCL;
  const int k = blockIdx.x - b * KCL;
  const int t = threadIdx.x;
  const float bk = bias[k];
  const int px0 = t * 8;
  const size_t SL = (size_t)KCL * HW;
  const unsigned short* pb = part + ((size_t)b * 4) * SL + (size_t)k * HW + px0;

  unsigned a0[4], a1[4], a2[4], a3[4];
  *reinterpret_cast<uint4*>(a0) = *reinterpret_cast<const uint4*>(pb);
  *reinterpret_cast<uint4*>(a1) = *reinterpret_cast<const uint4*>(pb + SL);
  *reinterpret_cast<uint4*>(a2) = *reinterpret_cast<const uint4*>(pb + 2 * SL);
  *reinterpret_cast<uint4*>(a3) = *reinterpret_cast<const uint4*>(pb + 3 * SL);

  float gs = 0.f;
  unsigned so[4];
  #pragma unroll
  for (int j = 0; j < 4; ++j) {
    float c0 = bk + bf_lo(a0[j]) + bf_lo(a1[j]) + bf_lo(a2[j]) + bf_lo(a3[j]);
    float c1 = bk + bf_hi(a0[j]) + bf_hi(a1[j]) + bf_hi(a2[j]) + bf_hi(a3[j]);
    gs += c0 + c1;
    float s0 = 1.f / (1.f + __expf(-c0));
    float s1 = 1.f / (1.f + __expf(-c1));
    so[j] = pack_bf16(s0, s1);
  }
  *reinterpret_cast<uint4*>(sig + ((size_t)b * 32 + k) * HW + px0) =
      *reinterpret_cast<uint4*>(so);

  const int lane = t & 63, wv = t >> 6;
  #pragma unroll
  for (int o = 1; o < 64; o <<= 1) gs += __shfl_xor(gs, o, 64);
  __shared__ float gr[8];
  if (lane == 0) gr[wv] = gs;
  __syncthreads();
  if (t == 0) {
    float s = gr[0] + gr[1] + gr[2] + gr[3] + gr[4] + gr[5] + gr[6] + gr[7];
    out_g[b * KCL + k] = s * (1.f / 4096.f);
  }
}

// K3: sf[b, :, chslab] = (1/4096) * x[chslab, :] @ sigT. MFMA, dbuf LDS march.
__global__ __launch_bounds__(512, 2)
void k3_sf(const float* __restrict__ x, const unsigned short* __restrict__ sig,
           float* __restrict__ out_sf) {
  extern __shared__ char smem[];  // 2 x 65536: bf16 [32ch][1024px], slot swz s^row
  const int t = threadIdx.x;
  const int lane = t & 63;
  const int wv = __builtin_amdgcn_readfirstlane(t >> 6);
  const int b = blockIdx.x >> 4;
  const int chs = blockIdx.x & 15;
  const float* xb = x + (size_t)(b * CCH + chs * 32) * HW;
  const int m = lane & 31;     // A: ch-row sub / B: cls row
  const int h = lane >> 5;     // k-half
  const unsigned short* sigrow = sig + ((size_t)b * 32 + m) * HW;

  f32x16 acc;
  #pragma unroll
  for (int i = 0; i < 16; ++i) acc[i] = 0.f;

  // prologue: stage step 0 into buf0
  #pragma unroll
  for (int j = 0; j < 16; ++j) {
    int mm = t + 512 * j;
    int row = mm >> 8;        // 0..31
    int q = mm & 255;         // float4 quad within 1024 px
    const float4 v = *reinterpret_cast<const float4*>(xb + (size_t)row * HW + q * 4);
    unsigned u0 = pack_bf16(v.x, v.y);
    unsigned u1 = pack_bf16(v.z, v.w);
    *reinterpret_cast<uint2*>(smem + row * 2048 + ((q >> 1) ^ row) * 16 + (q & 1) * 8) =
        make_uint2(u0, u1);
  }
  __syncthreads();

  int cur = 0;
  float4 stg[16];
  for (int step = 0; step < 4; ++step) {
    if (step < 3) {  // issue next-tile loads (held in regs across compute)
      #pragma unroll
      for (int j = 0; j < 16; ++j) {
        int mm = t + 512 * j;
        int row = mm >> 8;
        int q = mm & 255;
        stg[j] = *reinterpret_cast<const float4*>(
            xb + (size_t)row * HW + (step + 1) * 1024 + q * 4);
      }
    }
    const char* bufc = smem + cur * 65536;
    #pragma unroll
    for (int ks = 0; ks < 8; ++ks) {
      const int slin = wv * 16 + ks * 2 + h;  // 16B slot (8 px) within row
      const short8 a = *reinterpret_cast<const short8*>(bufc + m * 2048 + (slin ^ m) * 16);
      const short8 bb = *reinterpret_cast<const short8*>(
          sigrow + step * 1024 + wv * 128 + ks * 16 + h * 8);
      acc = __builtin_amdgcn_mfma_f32_32x32x16_bf16(a, bb, acc, 0, 0, 0);
    }
    if (step < 3) {
      char* bufn = smem + (cur ^ 1) * 65536;
      #pragma unroll
      for (int j = 0; j < 16; ++j) {
        int mm = t + 512 * j;
        int row = mm >> 8;
        int q = mm & 255;
        unsigned u0 = pack_bf16(stg[j].x, stg[j].y);
        unsigned u1 = pack_bf16(stg[j].z, stg[j].w);
        *reinterpret_cast<uint2*>(bufn + row * 2048 + ((q >> 1) ^ row) * 16 + (q & 1) * 8) =
            make_uint2(u0, u1);
      }
    }
    __syncthreads();
    cur ^= 1;
  }

  // epilogue: 8-wave K-split partial reduce via LDS, then direct sf store
  float* P = (float*)smem;  // [8][32cls * 32ch] f32 = 32 KB
  #pragma unroll
  for (int r = 0; r < 16; ++r) {
    const int chr = (r & 3) + 8 * (r >> 2) + 4 * h;  // validated C-row map
    P[wv * 1024 + m * 32 + chr] = acc[r];            // cls-major
  }
  __syncthreads();
  const float inv = 1.f / 4096.f;
  {
    float s = 0.f;
    #pragma unroll
    for (int w8 = 0; w8 < 8; ++w8) s += P[w8 * 1024 + t];
    const int n = t >> 5, ch = t & 31;               // n = 0..15
    out_sf[((size_t)b * KCL + n) * CCH + chs * 32 + ch] = s * inv;
    if (t < 32) {                                    // n = 16 row
      float s2 = 0.f;
      #pragma unroll
      for (int w8 = 0; w8 < 8; ++w8) s2 += P[w8 * 1024 + 512 + t];
      out_sf[((size_t)b * KCL + 16) * CCH + chs * 32 + t] = s2 * inv;
    }
  }
}

extern "C" void kernel_launch(void* const* d_in, const int* in_sizes, int n_in,
                              void* d_out, int out_size, void* d_ws, size_t ws_size,
                              hipStream_t stream) {
  const float* x = (const float*)d_in[0];
  const float* w = (const float*)d_in[1];
  const float* bias = (const float*)d_in[2];
  float* out = (float*)d_out;
  float* outg = out;                    // (32,17)
  float* outsf = out + BATCH * KCL;     // (32,17,512)

  char* ws = (char*)d_ws;
  float* wT = (float*)(ws + WT_OFF);
  unsigned short* part = (unsigned short*)(ws + PART_OFF);
  unsigned short* sig = (unsigned short*)(ws + SIG_OFF);

  transpose_w_kernel<<<1, 512, 0, stream>>>(w, wT);
  k1_campart<<<256, 512, 0, stream>>>(x, wT, part);
  k2_sig<<<BATCH * KCL, 512, 0, stream>>>(part, bias, outg, sig);
  hipFuncSetAttribute((const void*)k3_sf, hipFuncAttributeMaxDynamicSharedMemorySize, 131072);
  k3_sf<<<BATCH * 16, 512, 131072, stream>>>(x, sig, outsf);
}